// Round 6
// baseline (975.684 us; speedup 1.0000x reference)
//
#include <hip/hip_runtime.h>

#define H 128
#define ED 64
#define CH 16   // edges/nodes per MFMA tile

typedef __attribute__((ext_vector_type(8))) short short8;
typedef __attribute__((ext_vector_type(4))) float f32x4;

// stats layout: [0:128) colsum, [128:256) colsumsq, [256:384) scale, [384:512) shift
__device__ __align__(16) float g_stats[512];

__device__ __forceinline__ unsigned short f2bf(float f) {
    unsigned u = __float_as_uint(f);
    unsigned r = u + 0x7fffu + ((u >> 16) & 1u);   // RNE
    return (unsigned short)(r >> 16);
}
__device__ __forceinline__ float bf2f(unsigned short h) {
    return __uint_as_float(((unsigned)h) << 16);
}

__global__ void k_zero_stats() {
    if (threadIdx.x < 512) g_stats[threadIdx.x] = 0.f;
}

// ================= Edge kernel: natural order MFMA + atomic scatter ============
// tile = 16 edges. msg = relu(ea@We + h[src] + be); atomicAdd agg[dst] += msg.
// A lane mapping: row = lane&15, k = 8*(lane>>4)+b (+32 for 2nd K-step)
// C/D lane mapping: col = lane&15, row = 4*(lane>>4)+reg   (HW-verified r5)
__global__ __launch_bounds__(512, 4) void k_edge_a(
    const float* __restrict__ hN, const int* __restrict__ ei,
    const float* __restrict__ ea, const float* __restrict__ We,
    const float* __restrict__ be, float* __restrict__ agg, int E)
{
    __shared__ unsigned sWb[ED * H / 2];             // 16 KB bf16-packed We
    __shared__ __align__(16) short sBf[8][2][64][8]; // 16 KB B-fragments
    const int tid = threadIdx.x;
    for (int i = tid; i < ED * H / 2; i += 512) {
        float2 wv = ((const float2*)We)[i];
        sWb[i] = ((unsigned)f2bf(wv.y) << 16) | (unsigned)f2bf(wv.x);
    }
    __syncthreads();
    // all-thread B-fragment build: 1024 entries (t, s, lane)
    for (int idx = tid; idx < 8 * 2 * 64; idx += 512) {
        int t = idx >> 7, s = (idx >> 6) & 1, ll = idx & 63;
        int ra = ll & 15, kgg = ll >> 4;
        short8 f;
#pragma unroll
        for (int b = 0; b < 8; ++b) {
            int k = (s << 5) + (kgg << 3) + b;
            f[b] = ((const short*)sWb)[k * H + (t << 4) + ra];
        }
        *(short8*)&sBf[t][s][ll][0] = f;
    }
    const int l = tid & 63, w = tid >> 6;
    const int rA = l & 15, kg = l >> 4;
    float beT[8];
#pragma unroll
    for (int t = 0; t < 8; ++t) beT[t] = be[(t << 4) + rA];
    __syncthreads();

    const int nT = (E + CH - 1) / CH;
    const int gw = (blockIdx.x << 3) | w;
    const int nW = gridDim.x << 3;
    const int tpw = (nT + nW - 1) / nW;
    const int t0 = gw * tpw;
    const int t1 = min(t0 + tpw, nT);
    if (t0 >= nT) return;

    float4 An0, An1, An2, An3;
    int nS0, nS1, nS2, nS3, nD0, nD1, nD2, nD3;
    {   // prologue: tile t0 A + src/dst
        int e0 = t0 * CH;
        const float* ar = ea + (size_t)min(e0 + rA, E - 1) * ED + (kg << 3);
        An0 = *(const float4*)ar;        An1 = *(const float4*)(ar + 4);
        An2 = *(const float4*)(ar + 32); An3 = *(const float4*)(ar + 36);
        int r0 = min(e0 + (kg << 2) + 0, E - 1), r1 = min(e0 + (kg << 2) + 1, E - 1);
        int r2 = min(e0 + (kg << 2) + 2, E - 1), r3 = min(e0 + (kg << 2) + 3, E - 1);
        nS0 = ei[r0]; nS1 = ei[r1]; nS2 = ei[r2]; nS3 = ei[r3];
        nD0 = ei[E + r0]; nD1 = ei[E + r1]; nD2 = ei[E + r2]; nD3 = ei[E + r3];
    }

    for (int tt = t0; tt < t1; ++tt) {
        float4 a0 = An0, a1 = An1, a2 = An2, a3 = An3;
        int s0 = nS0, s1 = nS1, s2 = nS2, s3 = nS3;
        int d0 = nD0, d1 = nD1, d2 = nD2, d3 = nD3;

        // issue h gathers early (consumed after MFMA)
        float hv0[8], hv1[8], hv2[8], hv3[8];
        const float* hp0 = hN + (size_t)s0 * H + rA;
        const float* hp1 = hN + (size_t)s1 * H + rA;
        const float* hp2 = hN + (size_t)s2 * H + rA;
        const float* hp3 = hN + (size_t)s3 * H + rA;
#pragma unroll
        for (int t = 0; t < 8; ++t) {
            hv0[t] = hp0[t << 4]; hv1[t] = hp1[t << 4];
            hv2[t] = hp2[t << 4]; hv3[t] = hp3[t << 4];
        }
        // prefetch next tile (latency hides under cvt+MFMA+epilogue)
        if (tt + 1 < t1) {
            int e0 = (tt + 1) * CH;
            const float* ar = ea + (size_t)min(e0 + rA, E - 1) * ED + (kg << 3);
            An0 = *(const float4*)ar;        An1 = *(const float4*)(ar + 4);
            An2 = *(const float4*)(ar + 32); An3 = *(const float4*)(ar + 36);
            int r0 = min(e0 + (kg << 2) + 0, E - 1), r1 = min(e0 + (kg << 2) + 1, E - 1);
            int r2 = min(e0 + (kg << 2) + 2, E - 1), r3 = min(e0 + (kg << 2) + 3, E - 1);
            nS0 = ei[r0]; nS1 = ei[r1]; nS2 = ei[r2]; nS3 = ei[r3];
            nD0 = ei[E + r0]; nD1 = ei[E + r1]; nD2 = ei[E + r2]; nD3 = ei[E + r3];
        }

        // A fp32 -> bf16 fragments
        short8 A0, A1;
        A0[0] = f2bf(a0.x); A0[1] = f2bf(a0.y); A0[2] = f2bf(a0.z); A0[3] = f2bf(a0.w);
        A0[4] = f2bf(a1.x); A0[5] = f2bf(a1.y); A0[6] = f2bf(a1.z); A0[7] = f2bf(a1.w);
        A1[0] = f2bf(a2.x); A1[1] = f2bf(a2.y); A1[2] = f2bf(a2.z); A1[3] = f2bf(a2.w);
        A1[4] = f2bf(a3.x); A1[5] = f2bf(a3.y); A1[6] = f2bf(a3.z); A1[7] = f2bf(a3.w);

        f32x4 C[8];
#pragma unroll
        for (int t = 0; t < 8; ++t) {
            short8 b0 = *(const short8*)&sBf[t][0][l][0];
            short8 b1 = *(const short8*)&sBf[t][1][l][0];
            f32x4 c = __builtin_amdgcn_mfma_f32_16x16x32_bf16(
                A0, b0, (f32x4){0.f, 0.f, 0.f, 0.f}, 0, 0, 0);
            C[t] = __builtin_amdgcn_mfma_f32_16x16x32_bf16(A1, b1, c, 0, 0, 0);
        }

        // epilogue: relu(msg + h + be) -> atomic scatter
        const int m = E - tt * CH;
        const int r = kg << 2;
        const bool ok0 = (r + 0) < m, ok1 = (r + 1) < m;
        const bool ok2 = (r + 2) < m, ok3 = (r + 3) < m;
        float* q0 = agg + (size_t)d0 * H + rA;
        float* q1 = agg + (size_t)d1 * H + rA;
        float* q2 = agg + (size_t)d2 * H + rA;
        float* q3 = agg + (size_t)d3 * H + rA;
#pragma unroll
        for (int t = 0; t < 8; ++t) {
            float v0 = fmaxf(C[t][0] + hv0[t] + beT[t], 0.f);
            float v1 = fmaxf(C[t][1] + hv1[t] + beT[t], 0.f);
            float v2 = fmaxf(C[t][2] + hv2[t] + beT[t], 0.f);
            float v3 = fmaxf(C[t][3] + hv3[t] + beT[t], 0.f);
            if (ok0) atomicAdd(q0 + (t << 4), v0);
            if (ok1) atomicAdd(q1 + (t << 4), v1);
            if (ok2) atomicAdd(q2 + (t << 4), v2);
            if (ok3) atomicAdd(q3 + (t << 4), v3);
        }
    }
}

// ================= MLP layer 1 (MFMA, hi/lo activations) ======================
// reads h + agg(zb), writes y1 packed (bf16hi<<16 | bf16lo) in place over zb.
__global__ __launch_bounds__(256, 4) void k_mlp1(
    const float* __restrict__ hN, float* zb, const float* __restrict__ W1,
    const float* __restrict__ b1, const float* __restrict__ epsp, int N)
{
    __shared__ __align__(16) short sBf[8][4][64][8];   // 32 KB W1 frags
    const int tid = threadIdx.x;
    for (int idx = tid; idx < 8 * 4 * 64; idx += 256) {
        int t = idx >> 8, s = (idx >> 6) & 3, ll = idx & 63;
        int ra = ll & 15, kgg = ll >> 4;
        short8 f;
#pragma unroll
        for (int b = 0; b < 8; ++b) {
            int k = (s << 5) + (kgg << 3) + b;
            f[b] = (short)f2bf(W1[k * H + (t << 4) + ra]);
        }
        *(short8*)&sBf[t][s][ll][0] = f;
    }
    __syncthreads();
    const int l = tid & 63, w = tid >> 6;
    const int rA = l & 15, kg = l >> 4;
    const float e1 = 1.f + epsp[0];
    float bT[8];
#pragma unroll
    for (int t = 0; t < 8; ++t) bT[t] = b1[(t << 4) + rA];

    const int nT = (N + CH - 1) / CH;
    for (int tt = blockIdx.x * 4 + w; tt < nT; tt += gridDim.x * 4) {
        const int n0 = tt << 4;
        const int row = min(n0 + rA, N - 1);
        const float* hrow = hN + (size_t)row * H;
        const float* arow = (const float*)zb + (size_t)row * H;
        f32x4 C[8];
#pragma unroll
        for (int t = 0; t < 8; ++t) C[t] = (f32x4){0.f, 0.f, 0.f, 0.f};

#pragma unroll
        for (int s = 0; s < 4; ++s) {
            const float* hp = hrow + (s << 5) + (kg << 3);
            const float* ap = arow + (s << 5) + (kg << 3);
            float4 h0 = *(const float4*)hp;
            float4 h1 = *(const float4*)(hp + 4);
            float4 g0 = *(const float4*)ap;
            float4 g1 = *(const float4*)(ap + 4);
            float z[8];
            z[0] = fmaf(e1, h0.x, g0.x); z[1] = fmaf(e1, h0.y, g0.y);
            z[2] = fmaf(e1, h0.z, g0.z); z[3] = fmaf(e1, h0.w, g0.w);
            z[4] = fmaf(e1, h1.x, g1.x); z[5] = fmaf(e1, h1.y, g1.y);
            z[6] = fmaf(e1, h1.z, g1.z); z[7] = fmaf(e1, h1.w, g1.w);
            short8 ah, al;
#pragma unroll
            for (int j = 0; j < 8; ++j) {
                unsigned short hi = f2bf(z[j]);
                ah[j] = (short)hi;
                al[j] = (short)f2bf(z[j] - bf2f(hi));
            }
#pragma unroll
            for (int t = 0; t < 8; ++t) {
                short8 B = *(const short8*)&sBf[t][s][l][0];
                C[t] = __builtin_amdgcn_mfma_f32_16x16x32_bf16(ah, B, C[t], 0, 0, 0);
                C[t] = __builtin_amdgcn_mfma_f32_16x16x32_bf16(al, B, C[t], 0, 0, 0);
            }
        }
        // epilogue: y1 = relu(C+b1) -> pack hi/lo -> in-place store
#pragma unroll
        for (int t = 0; t < 8; ++t) {
#pragma unroll
            for (int rg = 0; rg < 4; ++rg) {
                int n = n0 + (kg << 2) + rg;
                float y = fmaxf(C[t][rg] + bT[t], 0.f);
                unsigned short hi = f2bf(y);
                unsigned short lo = f2bf(y - bf2f(hi));
                if (n < N)
                    ((unsigned*)zb)[(size_t)n * H + (t << 4) + rA] =
                        ((unsigned)hi << 16) | (unsigned)lo;
            }
        }
    }
}

// ================= MLP layer 2 + BN stats (MFMA, hi/lo activations) ===========
__global__ __launch_bounds__(256, 4) void k_mlp2(
    float* zb, const float* __restrict__ W2, const float* __restrict__ b2, int N)
{
    __shared__ __align__(16) short sBf[8][4][64][8];   // 32 KB W2 frags
    const int tid = threadIdx.x;
    for (int idx = tid; idx < 8 * 4 * 64; idx += 256) {
        int t = idx >> 8, s = (idx >> 6) & 3, ll = idx & 63;
        int ra = ll & 15, kgg = ll >> 4;
        short8 f;
#pragma unroll
        for (int b = 0; b < 8; ++b) {
            int k = (s << 5) + (kgg << 3) + b;
            f[b] = (short)f2bf(W2[k * H + (t << 4) + ra]);
        }
        *(short8*)&sBf[t][s][ll][0] = f;
    }
    __syncthreads();
    const int l = tid & 63, w = tid >> 6;
    const int rA = l & 15, kg = l >> 4;
    float bT[8];
#pragma unroll
    for (int t = 0; t < 8; ++t) bT[t] = b2[(t << 4) + rA];
    float ps[8], pq[8];
#pragma unroll
    for (int t = 0; t < 8; ++t) { ps[t] = 0.f; pq[t] = 0.f; }

    const int nT = (N + CH - 1) / CH;
    for (int tt = blockIdx.x * 4 + w; tt < nT; tt += gridDim.x * 4) {
        const int n0 = tt << 4;
        const int row = min(n0 + rA, N - 1);
        const unsigned* yrow = (const unsigned*)zb + (size_t)row * H;
        f32x4 C[8];
#pragma unroll
        for (int t = 0; t < 8; ++t) C[t] = (f32x4){0.f, 0.f, 0.f, 0.f};

#pragma unroll
        for (int s = 0; s < 4; ++s) {
            const unsigned* yp = yrow + (s << 5) + (kg << 3);
            uint4 u0 = *(const uint4*)yp;
            uint4 u1 = *(const uint4*)(yp + 4);
            short8 ah, al;
            ah[0] = (short)(u0.x >> 16); al[0] = (short)(u0.x & 0xffffu);
            ah[1] = (short)(u0.y >> 16); al[1] = (short)(u0.y & 0xffffu);
            ah[2] = (short)(u0.z >> 16); al[2] = (short)(u0.z & 0xffffu);
            ah[3] = (short)(u0.w >> 16); al[3] = (short)(u0.w & 0xffffu);
            ah[4] = (short)(u1.x >> 16); al[4] = (short)(u1.x & 0xffffu);
            ah[5] = (short)(u1.y >> 16); al[5] = (short)(u1.y & 0xffffu);
            ah[6] = (short)(u1.z >> 16); al[6] = (short)(u1.z & 0xffffu);
            ah[7] = (short)(u1.w >> 16); al[7] = (short)(u1.w & 0xffffu);
#pragma unroll
            for (int t = 0; t < 8; ++t) {
                short8 B = *(const short8*)&sBf[t][s][l][0];
                C[t] = __builtin_amdgcn_mfma_f32_16x16x32_bf16(ah, B, C[t], 0, 0, 0);
                C[t] = __builtin_amdgcn_mfma_f32_16x16x32_bf16(al, B, C[t], 0, 0, 0);
            }
        }
        // epilogue: z2 = relu(C+b2); in-place store; BN partials
#pragma unroll
        for (int t = 0; t < 8; ++t) {
#pragma unroll
            for (int rg = 0; rg < 4; ++rg) {
                int n = n0 + (kg << 2) + rg;
                float z2 = fmaxf(C[t][rg] + bT[t], 0.f);
                bool v = (n < N);
                if (v) ((float*)zb)[(size_t)n * H + (t << 4) + rA] = z2;
                float zc = v ? z2 : 0.f;
                ps[t] += zc;
                pq[t] += zc * zc;
            }
        }
    }
    // per-wave reduction over row-groups, then one atomic set
#pragma unroll
    for (int t = 0; t < 8; ++t) {
        float a = ps[t]; a += __shfl_xor(a, 16); a += __shfl_xor(a, 32); ps[t] = a;
        float b = pq[t]; b += __shfl_xor(b, 16); b += __shfl_xor(b, 32); pq[t] = b;
    }
    if (l < 16) {
#pragma unroll
        for (int t = 0; t < 8; ++t) {
            atomicAdd(&g_stats[(t << 4) + l], ps[t]);
            atomicAdd(&g_stats[128 + (t << 4) + l], pq[t]);
        }
    }
}

// ================= BN finalize =================
__global__ void k_bnfin(const float* __restrict__ gamma, const float* __restrict__ beta,
                        float invN)
{
    int t = threadIdx.x;
    float mean = g_stats[t] * invN;
    float var  = g_stats[H + t] * invN - mean * mean;
    float sc = gamma[t] * rsqrtf(var + 1e-5f);
    g_stats[256 + t] = sc;
    g_stats[384 + t] = beta[t] - mean * sc;
}

// ================= Final: out = (h + z2*scale + shift) * valid ================
__global__ void k_final(const float* __restrict__ hN, const float* __restrict__ valid,
                        float* __restrict__ out, int N)
{
    const int total = N * (H / 4);
    for (int i = blockIdx.x * blockDim.x + threadIdx.x; i < total;
         i += gridDim.x * blockDim.x) {
        int col4 = i & 31;
        int n = i >> 5;
        float4 z = ((float4*)out)[i];
        float4 hv = ((const float4*)hN)[i];
        float4 sc = *(const float4*)&g_stats[256 + col4 * 4];
        float4 sh = *(const float4*)&g_stats[384 + col4 * 4];
        float vf = valid[n];
        float4 r;
        r.x = (hv.x + fmaf(z.x, sc.x, sh.x)) * vf;
        r.y = (hv.y + fmaf(z.y, sc.y, sh.y)) * vf;
        r.z = (hv.z + fmaf(z.z, sc.z, sh.z)) * vf;
        r.w = (hv.w + fmaf(z.w, sc.w, sh.w)) * vf;
        ((float4*)out)[i] = r;
    }
}

extern "C" void kernel_launch(void* const* d_in, const int* in_sizes, int n_in,
                              void* d_out, int out_size, void* d_ws, size_t ws_size,
                              hipStream_t stream) {
    const float* hN    = (const float*)d_in[0];
    const int*   ei    = (const int*)d_in[1];
    const float* ea    = (const float*)d_in[2];
    const float* valid = (const float*)d_in[3];
    const float* We    = (const float*)d_in[4];
    const float* be    = (const float*)d_in[5];
    const float* W1    = (const float*)d_in[6];
    const float* b1    = (const float*)d_in[7];
    const float* W2    = (const float*)d_in[8];
    const float* b2    = (const float*)d_in[9];
    const float* epsg  = (const float*)d_in[10];
    const float* gamma = (const float*)d_in[11];
    const float* beta  = (const float*)d_in[12];
    float* out = (float*)d_out;

    const int N = in_sizes[0] / H;
    const int E = in_sizes[1] / 2;

    k_zero_stats<<<1, 512, 0, stream>>>();
    hipMemsetAsync(d_out, 0, (size_t)out_size * sizeof(float), stream);
    k_edge_a<<<1024, 512, 0, stream>>>(hN, ei, ea, We, be, out, E);
    k_mlp1<<<512, 256, 0, stream>>>(hN, out, W1, b1, epsg, N);
    k_mlp2<<<512, 256, 0, stream>>>(out, W2, b2, N);
    k_bnfin<<<1, 128, 0, stream>>>(gamma, beta, 1.0f / (float)N);
    k_final<<<2048, 256, 0, stream>>>(hN, valid, out, N);
}